// Round 6
// baseline (155.026 us; speedup 1.0000x reference)
//
#include <hip/hip_runtime.h>
#include <cmath>

#define NQ 32
#define H 512
#define NOFF 496
#define NR4 528   // NQ + NOFF

__device__ __forceinline__ float sigmoidf(float x) {
    return 1.0f / (1.0f + __expf(-x));
}
__device__ __forceinline__ float dot4(float4 a, float4 b) {
    return a.x * b.x + a.y * b.y + a.z * b.z + a.w * b.w;
}
__device__ __forceinline__ float ldagent(const float* p) {
    return __hip_atomic_load(p, __ATOMIC_RELAXED, __HIP_MEMORY_SCOPE_AGENT);
}
__device__ __forceinline__ float red16(float a) {
    a += __shfl_xor(a, 1, 64);
    a += __shfl_xor(a, 2, 64);
    a += __shfl_xor(a, 4, 64);
    a += __shfl_xor(a, 8, 64);
    return a;
}

// ---------------- KA: layer1 (in-block) + layer2 GEMV ----------------
// grid 272 = 34 cols x 8 row-blocks. col 0: h2 rows; 1..32: raw jacobian col;
// 33: g-chain (g1 in-block, g2 rows).
__global__ void __launch_bounds__(256) ka(
    const float* __restrict__ q,
    const float* __restrict__ W1, const float* __restrict__ b1,
    const float* __restrict__ W2, const float* __restrict__ b2,
    const float* __restrict__ Wg1, const float* __restrict__ bg1,
    const float* __restrict__ Wg2, const float* __restrict__ bg2,
    float* __restrict__ Y, float* __restrict__ g2)
{
    const int c = blockIdx.x >> 3, rb = blockIdx.x & 7;
    const int tid = threadIdx.x;
    const int lane = tid & 63, w = tid >> 6;
    const int p = lane & 15, rg = lane >> 4;
    const bool isg = (c == 33);

    __shared__ float qs[NQ];
    __shared__ float bcol[H];

    if (tid < NQ) qs[tid] = q[tid];
    __syncthreads();

    const float* Wf = isg ? Wg1 : W1;
    const float* bf = isg ? bg1 : b1;
    for (int j = tid; j < H; j += 256) {
        const float4* wr = (const float4*)(Wf + j * NQ);
        float acc = 0.f;
        #pragma unroll
        for (int cc = 0; cc < 8; ++cc) {
            float4 wv = wr[cc];
            acc += wv.x * qs[4*cc] + wv.y * qs[4*cc+1] + wv.z * qs[4*cc+2] + wv.w * qs[4*cc+3];
        }
        float h = sigmoidf(acc + bf[j]);
        bcol[j] = (c == 0 || isg) ? h : h * (1.f - h) * Wf[j * NQ + (c - 1)];
    }
    __syncthreads();

    const float4* b4 = (const float4*)bcol;
    float4 bb[8];
    #pragma unroll
    for (int i = 0; i < 8; ++i) bb[i] = b4[p + 16 * i];

    const float4* Wv = (const float4*)(isg ? Wg2 : W2);
    const int r0 = rb * 64;
    #pragma unroll 2
    for (int pass = 0; pass < 4; ++pass) {
        int r = r0 + pass * 16 + w * 4 + rg;
        const float4* wr = Wv + (size_t)r * (H / 4);
        float4 wreg[8];
        #pragma unroll
        for (int i = 0; i < 8; ++i) wreg[i] = wr[p + 16 * i];
        float a = 0.f;
        #pragma unroll
        for (int i = 0; i < 8; ++i) a += dot4(wreg[i], bb[i]);
        a = red16(a);
        if (p == 0) {
            if (c == 0)      Y[r] = sigmoidf(a + b2[r]);          // h2 (post-act)
            else if (!isg)   Y[c * H + r] = a;                    // raw jacobian col
            else             g2[r] = sigmoidf(a + bg2[r]);        // g2 (post-act)
        }
    }
}

// ---------------- KB: layer3 GEMV ----------------
// grid 265 = 33 cols x 8 rbs + 1 g-block (gvec).
__global__ void __launch_bounds__(256) kb(
    const float* __restrict__ W3, const float* __restrict__ b3,
    const float* __restrict__ Wg3, const float* __restrict__ bg3,
    const float* __restrict__ Y, const float* __restrict__ g2,
    float* __restrict__ Z, float* __restrict__ gvec)
{
    const int tid = threadIdx.x;
    const int lane = tid & 63, w = tid >> 6;
    const int p = lane & 15, rg = lane >> 4;

    if (blockIdx.x == 264) {   // gvec = Wg3 @ g2 + bg3 (32 rows)
        const float4* g4 = (const float4*)g2;
        float4 bb[8];
        #pragma unroll
        for (int i = 0; i < 8; ++i) bb[i] = g4[p + 16 * i];
        #pragma unroll
        for (int pass = 0; pass < 2; ++pass) {
            int r = pass * 16 + w * 4 + rg;
            const float4* wr = (const float4*)Wg3 + (size_t)r * (H / 4);
            float4 wreg[8];
            #pragma unroll
            for (int i = 0; i < 8; ++i) wreg[i] = wr[p + 16 * i];
            float a = 0.f;
            #pragma unroll
            for (int i = 0; i < 8; ++i) a += dot4(wreg[i], bb[i]);
            a = red16(a);
            if (p == 0) gvec[r] = a + bg3[r];
        }
        return;
    }

    const int c = blockIdx.x >> 3, rb = blockIdx.x & 7;
    const float4* Y0 = (const float4*)Y;            // h2 post-act
    const float4* Yc = (const float4*)(Y + c * H);  // raw col (c>0)
    float4 bb[8];
    #pragma unroll
    for (int i = 0; i < 8; ++i) {
        float4 h = Y0[p + 16 * i];
        if (c == 0) bb[i] = h;
        else {
            float4 yc = Yc[p + 16 * i];
            bb[i] = make_float4(h.x*(1.f-h.x)*yc.x, h.y*(1.f-h.y)*yc.y,
                                h.z*(1.f-h.z)*yc.z, h.w*(1.f-h.w)*yc.w);
        }
    }
    const int r0 = rb * 64;
    #pragma unroll 2
    for (int pass = 0; pass < 4; ++pass) {
        int r = r0 + pass * 16 + w * 4 + rg;
        const float4* wr = (const float4*)W3 + (size_t)r * (H / 4);
        float4 wreg[8];
        #pragma unroll
        for (int i = 0; i < 8; ++i) wreg[i] = wr[p + 16 * i];
        float a = 0.f;
        #pragma unroll
        for (int i = 0; i < 8; ++i) a += dot4(wreg[i], bb[i]);
        a = red16(a);
        if (p == 0) {
            if (c == 0) Z[r] = sigmoidf(a + b3[r]);   // h3 (post-act)
            else        Z[c * H + r] = a;
        }
    }
}

// ---------------- KC: layer4 GEMV + fan-in assembly ----------------
// grid 264 = 33 cols x 8 rbs (66 rows each). Last block assembles tau.
__global__ void __launch_bounds__(256) kc(
    const float* __restrict__ Wd, const float* __restrict__ bd,
    const float* __restrict__ Wo, const float* __restrict__ bo,
    const float* __restrict__ Z,
    const float* __restrict__ q_t, const float* __restrict__ q_tt,
    const float* __restrict__ gvec,
    float* __restrict__ U, unsigned* __restrict__ done,
    float* __restrict__ out)
{
    const int c = blockIdx.x >> 3, rb = blockIdx.x & 7;
    const int tid = threadIdx.x;
    const int lane = tid & 63, w = tid >> 6;
    const int p = lane & 15, rg = lane >> 4;

    __shared__ float ldiag[NQ], loff[NOFF], vv[NR4];
    __shared__ float Lm[NQ][NQ + 1], Dq[NQ][NQ + 1], Fj[NQ][NQ + 1];
    __shared__ float qts[NQ], qtts[NQ], LTq[NQ], t1s[NQ], u2[NQ];
    __shared__ int amLast;

    {
        const float4* Z0 = (const float4*)Z;            // h3 post-act
        const float4* Zc = (const float4*)(Z + c * H);
        float4 bb[8];
        #pragma unroll
        for (int i = 0; i < 8; ++i) {
            float4 h = Z0[p + 16 * i];
            if (c == 0) bb[i] = h;
            else {
                float4 zc = Zc[p + 16 * i];
                bb[i] = make_float4(h.x*(1.f-h.x)*zc.x, h.y*(1.f-h.y)*zc.y,
                                    h.z*(1.f-h.z)*zc.z, h.w*(1.f-h.w)*zc.w);
            }
        }
        #pragma unroll 2
        for (int pass = 0; pass < 5; ++pass) {
            int idx = pass * 16 + w * 4 + rg;
            if (idx < 66) {
                int r = rb * 66 + idx;
                const float4* wr = (r < NQ) ? ((const float4*)Wd + (size_t)r * (H / 4))
                                            : ((const float4*)Wo + (size_t)(r - NQ) * (H / 4));
                float4 wreg[8];
                #pragma unroll
                for (int i = 0; i < 8; ++i) wreg[i] = wr[p + 16 * i];
                float a = 0.f;
                #pragma unroll
                for (int i = 0; i < 8; ++i) a += dot4(wreg[i], bb[i]);
                a = red16(a);
                if (p == 0) U[c * NR4 + r] = a;
            }
        }
    }

    __threadfence();
    __syncthreads();
    if (tid == 0) {
        unsigned old = __hip_atomic_fetch_add(done, 1u, __ATOMIC_ACQ_REL, __HIP_MEMORY_SCOPE_AGENT);
        amLast = (old == 263u) ? 1 : 0;
    }
    __syncthreads();
    if (!amLast) return;

    // ---- assembly (one block, 256 threads) ----
    if (tid < NQ) {
        ldiag[tid] = __expf(ldagent(&U[tid]) + bd[tid]);
        qts[tid]  = q_t[tid];
        qtts[tid] = q_tt[tid];
    }
    for (int r = tid; r < NOFF; r += 256)
        loff[r] = ldagent(&U[NQ + r]) + bo[r];
    __syncthreads();
    for (int m = tid; m < NR4; m += 256) {
        float acc = 0.f;
        #pragma unroll
        for (int kk = 0; kk < NQ; ++kk)
            acc += ldagent(&U[(kk + 1) * NR4 + m]) * qts[kk];
        vv[m] = (m < NQ) ? ldiag[m] * acc : acc;
    }
    for (int pp = tid; pp < NQ * NQ; pp += 256) {
        int i = pp >> 5, j = pp & 31;
        Lm[i][j] = (i == j) ? ldiag[i]
                 : (j < i ? loff[i * (i - 1) / 2 + j] : 0.f);
    }
    for (int pp = tid; pp < NQ * NQ; pp += 256) {
        int j = pp >> 5, kk = pp & 31;
        const float* Uc = U + (kk + 1) * NR4;
        float acc = qts[j] * ldiag[j] * ldagent(&Uc[j]);
        for (int i = j + 1; i < NQ; ++i)
            acc += qts[i] * ldagent(&Uc[NQ + i * (i - 1) / 2 + j]);
        Fj[j][kk] = acc;
    }
    __syncthreads();
    for (int pp = tid; pp < NQ * NQ; pp += 256) {
        int i = pp >> 5, j = pp & 31;
        Dq[i][j] = (i == j) ? vv[i]
                 : (j < i ? vv[NQ + i * (i - 1) / 2 + j] : 0.f);
    }
    if (tid < NQ) {
        int kcol = tid;
        float a = 0.f, bsum = 0.f;
        #pragma unroll
        for (int j = 0; j < NQ; ++j) {
            a    += Lm[j][kcol] * qts[j];
            bsum += Lm[j][kcol] * qtts[j];
        }
        LTq[kcol] = a;
        t1s[kcol] = bsum;
    }
    __syncthreads();
    if (tid < NQ) {
        int kcol = tid;
        float a = 0.f;
        #pragma unroll
        for (int j = 0; j < NQ; ++j) a += Dq[j][kcol] * qts[j];
        u2[kcol] = a;
    }
    __syncthreads();
    if (tid < NQ) {
        int i = tid;
        float c1 = 0.f, c2 = 0.f, c3 = 0.f, c4 = 0.f;
        #pragma unroll
        for (int kk = 0; kk < NQ; ++kk) {
            c1 += Lm[i][kk] * t1s[kk];
            c2 += Lm[i][kk] * u2[kk];
            c3 += Dq[i][kk] * LTq[kk];
            c4 += Fj[i][kk] * LTq[kk];
        }
        out[i] = c1 + c2 + 0.5f * c3 - 0.5f * c4 + gvec[i];
    }
}

extern "C" void kernel_launch(void* const* d_in, const int* in_sizes, int n_in,
                              void* d_out, int out_size, void* d_ws, size_t ws_size,
                              hipStream_t stream) {
    const float* q    = (const float*)d_in[0];
    const float* q_t  = (const float*)d_in[1];
    const float* q_tt = (const float*)d_in[2];
    const float* W1   = (const float*)d_in[3];
    const float* b1   = (const float*)d_in[4];
    const float* W2   = (const float*)d_in[5];
    const float* b2   = (const float*)d_in[6];
    const float* W3   = (const float*)d_in[7];
    const float* b3   = (const float*)d_in[8];
    const float* Wd   = (const float*)d_in[9];
    const float* bd   = (const float*)d_in[10];
    const float* Wo   = (const float*)d_in[11];
    const float* bo   = (const float*)d_in[12];
    const float* Wg1  = (const float*)d_in[13];
    const float* bg1  = (const float*)d_in[14];
    const float* Wg2  = (const float*)d_in[15];
    const float* bg2  = (const float*)d_in[16];
    const float* Wg3  = (const float*)d_in[17];
    const float* bg3  = (const float*)d_in[18];

    float* ws = (float*)d_ws;
    float* Y       = ws;                   // 33*512 = 16896 (col 0 = h2)
    float* g2      = ws + 16896;           // 512
    float* Z       = ws + 17408;           // 33*512 = 16896 (col 0 = h3)
    float* gvec    = ws + 34304;           // 32
    float* U       = ws + 34336;           // 33*528 = 17424
    unsigned* done = (unsigned*)(ws + 51760);
    float* out     = (float*)d_out;

    hipMemsetAsync(done, 0, sizeof(unsigned), stream);
    hipLaunchKernelGGL(ka, dim3(272), dim3(256), 0, stream,
                       q, W1, b1, W2, b2, Wg1, bg1, Wg2, bg2, Y, g2);
    hipLaunchKernelGGL(kb, dim3(265), dim3(256), 0, stream,
                       W3, b3, Wg3, bg3, Y, g2, Z, gvec);
    hipLaunchKernelGGL(kc, dim3(264), dim3(256), 0, stream,
                       Wd, bd, Wo, bo, Z, q_t, q_tt, gvec, U, done, out);
}

// Round 7
// 129.517 us; speedup vs baseline: 1.1970x; 1.1970x over previous
//
#include <hip/hip_runtime.h>
#include <cmath>

#define NQ 32
#define H 512
#define NOFF 496
#define NR4 528   // NQ + NOFF

__device__ __forceinline__ float sigmoidf(float x) {
    return 1.0f / (1.0f + __expf(-x));
}
__device__ __forceinline__ float dot4(float4 a, float4 b) {
    return a.x * b.x + a.y * b.y + a.z * b.z + a.w * b.w;
}
__device__ __forceinline__ float red16(float a) {
    a += __shfl_xor(a, 1, 64);
    a += __shfl_xor(a, 2, 64);
    a += __shfl_xor(a, 4, 64);
    a += __shfl_xor(a, 8, 64);
    return a;
}

// ---------------- KA: layer1 (in-block) + layer2 GEMV ----------------
// grid 272 = 34 cols x 8 row-blocks; rb == blockIdx&7 == XCD id -> each XCD
// caches only its 64-row slice of W2.
__global__ void __launch_bounds__(256) ka(
    const float* __restrict__ q,
    const float* __restrict__ W1, const float* __restrict__ b1,
    const float* __restrict__ W2, const float* __restrict__ b2,
    const float* __restrict__ Wg1, const float* __restrict__ bg1,
    const float* __restrict__ Wg2, const float* __restrict__ bg2,
    float* __restrict__ Y, float* __restrict__ g2)
{
    const int c = blockIdx.x >> 3, rb = blockIdx.x & 7;
    const int tid = threadIdx.x;
    const int lane = tid & 63, w = tid >> 6;
    const int p = lane & 15, rg = lane >> 4;
    const bool isg = (c == 33);

    __shared__ float qs[NQ];
    __shared__ float bcol[H];

    if (tid < NQ) qs[tid] = q[tid];
    __syncthreads();

    const float* Wf = isg ? Wg1 : W1;
    const float* bf = isg ? bg1 : b1;
    for (int j = tid; j < H; j += 256) {
        const float4* wr = (const float4*)(Wf + j * NQ);
        float acc = 0.f;
        #pragma unroll
        for (int cc = 0; cc < 8; ++cc) {
            float4 wv = wr[cc];
            acc += wv.x * qs[4*cc] + wv.y * qs[4*cc+1] + wv.z * qs[4*cc+2] + wv.w * qs[4*cc+3];
        }
        float h = sigmoidf(acc + bf[j]);
        bcol[j] = (c == 0 || isg) ? h : h * (1.f - h) * Wf[j * NQ + (c - 1)];
    }
    __syncthreads();

    const float4* b4 = (const float4*)bcol;
    float4 bb[8];
    #pragma unroll
    for (int i = 0; i < 8; ++i) bb[i] = b4[p + 16 * i];

    const float4* Wv = (const float4*)(isg ? Wg2 : W2);
    const int r0 = rb * 64;
    #pragma unroll 2
    for (int pass = 0; pass < 4; ++pass) {
        int r = r0 + pass * 16 + w * 4 + rg;
        const float4* wr = Wv + (size_t)r * (H / 4);
        float4 wreg[8];
        #pragma unroll
        for (int i = 0; i < 8; ++i) wreg[i] = wr[p + 16 * i];
        float a = 0.f;
        #pragma unroll
        for (int i = 0; i < 8; ++i) a += dot4(wreg[i], bb[i]);
        a = red16(a);
        if (p == 0) {
            if (c == 0)      Y[r] = sigmoidf(a + b2[r]);          // h2 (post-act)
            else if (!isg)   Y[c * H + r] = a;                    // raw jacobian col
            else             g2[r] = sigmoidf(a + bg2[r]);        // g2 (post-act)
        }
    }
}

// ---------------- KB: layer3 GEMV ----------------
// grid 265 = 33 cols x 8 rbs + 1 g-block (gvec).
__global__ void __launch_bounds__(256) kb(
    const float* __restrict__ W3, const float* __restrict__ b3,
    const float* __restrict__ Wg3, const float* __restrict__ bg3,
    const float* __restrict__ Y, const float* __restrict__ g2,
    float* __restrict__ Z, float* __restrict__ gvec)
{
    const int tid = threadIdx.x;
    const int lane = tid & 63, w = tid >> 6;
    const int p = lane & 15, rg = lane >> 4;

    if (blockIdx.x == 264) {   // gvec = Wg3 @ g2 + bg3 (32 rows)
        const float4* g4 = (const float4*)g2;
        float4 bb[8];
        #pragma unroll
        for (int i = 0; i < 8; ++i) bb[i] = g4[p + 16 * i];
        #pragma unroll
        for (int pass = 0; pass < 2; ++pass) {
            int r = pass * 16 + w * 4 + rg;
            const float4* wr = (const float4*)Wg3 + (size_t)r * (H / 4);
            float4 wreg[8];
            #pragma unroll
            for (int i = 0; i < 8; ++i) wreg[i] = wr[p + 16 * i];
            float a = 0.f;
            #pragma unroll
            for (int i = 0; i < 8; ++i) a += dot4(wreg[i], bb[i]);
            a = red16(a);
            if (p == 0) gvec[r] = a + bg3[r];
        }
        return;
    }

    const int c = blockIdx.x >> 3, rb = blockIdx.x & 7;
    const float4* Y0 = (const float4*)Y;            // h2 post-act
    const float4* Yc = (const float4*)(Y + c * H);  // raw col (c>0)
    float4 bb[8];
    #pragma unroll
    for (int i = 0; i < 8; ++i) {
        float4 h = Y0[p + 16 * i];
        if (c == 0) bb[i] = h;
        else {
            float4 yc = Yc[p + 16 * i];
            bb[i] = make_float4(h.x*(1.f-h.x)*yc.x, h.y*(1.f-h.y)*yc.y,
                                h.z*(1.f-h.z)*yc.z, h.w*(1.f-h.w)*yc.w);
        }
    }
    const int r0 = rb * 64;
    #pragma unroll 2
    for (int pass = 0; pass < 4; ++pass) {
        int r = r0 + pass * 16 + w * 4 + rg;
        const float4* wr = (const float4*)W3 + (size_t)r * (H / 4);
        float4 wreg[8];
        #pragma unroll
        for (int i = 0; i < 8; ++i) wreg[i] = wr[p + 16 * i];
        float a = 0.f;
        #pragma unroll
        for (int i = 0; i < 8; ++i) a += dot4(wreg[i], bb[i]);
        a = red16(a);
        if (p == 0) {
            if (c == 0) Z[r] = sigmoidf(a + b3[r]);   // h3 (post-act)
            else        Z[c * H + r] = a;
        }
    }
}

// ---------------- KC: layer4 GEMV only (plain stores, no protocol) ----------------
// grid 264 = 33 cols x 8 rbs (66 rows each).
__global__ void __launch_bounds__(256) kc(
    const float* __restrict__ Wd, const float* __restrict__ Wo,
    const float* __restrict__ Z,
    float* __restrict__ U)
{
    const int c = blockIdx.x >> 3, rb = blockIdx.x & 7;
    const int tid = threadIdx.x;
    const int lane = tid & 63, w = tid >> 6;
    const int p = lane & 15, rg = lane >> 4;

    const float4* Z0 = (const float4*)Z;            // h3 post-act
    const float4* Zc = (const float4*)(Z + c * H);
    float4 bb[8];
    #pragma unroll
    for (int i = 0; i < 8; ++i) {
        float4 h = Z0[p + 16 * i];
        if (c == 0) bb[i] = h;
        else {
            float4 zc = Zc[p + 16 * i];
            bb[i] = make_float4(h.x*(1.f-h.x)*zc.x, h.y*(1.f-h.y)*zc.y,
                                h.z*(1.f-h.z)*zc.z, h.w*(1.f-h.w)*zc.w);
        }
    }
    #pragma unroll 2
    for (int pass = 0; pass < 5; ++pass) {
        int idx = pass * 16 + w * 4 + rg;
        if (idx < 66) {
            int r = rb * 66 + idx;
            const float4* wr = (r < NQ) ? ((const float4*)Wd + (size_t)r * (H / 4))
                                        : ((const float4*)Wo + (size_t)(r - NQ) * (H / 4));
            float4 wreg[8];
            #pragma unroll
            for (int i = 0; i < 8; ++i) wreg[i] = wr[p + 16 * i];
            float a = 0.f;
            #pragma unroll
            for (int i = 0; i < 8; ++i) a += dot4(wreg[i], bb[i]);
            a = red16(a);
            if (p == 0) U[c * NR4 + r] = a;
        }
    }
}

// ---------------- KD: assembly (1 block, plain cached loads) ----------------
__global__ void __launch_bounds__(256) kd(
    const float* __restrict__ U,
    const float* __restrict__ bd, const float* __restrict__ bo,
    const float* __restrict__ q_t, const float* __restrict__ q_tt,
    const float* __restrict__ gvec,
    float* __restrict__ out)
{
    const int tid = threadIdx.x;
    __shared__ float ldiag[NQ], loff[NOFF], vv[NR4];
    __shared__ float Lm[NQ][NQ + 1], Dq[NQ][NQ + 1], Fj[NQ][NQ + 1];
    __shared__ float qts[NQ], qtts[NQ], LTq[NQ], t1s[NQ], u2[NQ];

    if (tid < NQ) {
        ldiag[tid] = __expf(U[tid] + bd[tid]);
        qts[tid]  = q_t[tid];
        qtts[tid] = q_tt[tid];
    }
    for (int r = tid; r < NOFF; r += 256)
        loff[r] = U[NQ + r] + bo[r];
    __syncthreads();
    // vv streams all of U(cols 1..32) coalesced; warms L1/L2 for Fj.
    for (int m = tid; m < NR4; m += 256) {
        float acc = 0.f;
        #pragma unroll
        for (int kk = 0; kk < NQ; ++kk)
            acc += U[(kk + 1) * NR4 + m] * qts[kk];
        vv[m] = (m < NQ) ? ldiag[m] * acc : acc;
    }
    for (int pp = tid; pp < NQ * NQ; pp += 256) {
        int i = pp >> 5, j = pp & 31;
        Lm[i][j] = (i == j) ? ldiag[i]
                 : (j < i ? loff[i * (i - 1) / 2 + j] : 0.f);
    }
    for (int pp = tid; pp < NQ * NQ; pp += 256) {
        int j = pp >> 5, kk = pp & 31;
        const float* Uc = U + (kk + 1) * NR4;
        float acc = qts[j] * ldiag[j] * Uc[j];
        for (int i = j + 1; i < NQ; ++i)
            acc += qts[i] * Uc[NQ + i * (i - 1) / 2 + j];
        Fj[j][kk] = acc;
    }
    __syncthreads();
    for (int pp = tid; pp < NQ * NQ; pp += 256) {
        int i = pp >> 5, j = pp & 31;
        Dq[i][j] = (i == j) ? vv[i]
                 : (j < i ? vv[NQ + i * (i - 1) / 2 + j] : 0.f);
    }
    if (tid < NQ) {
        int kcol = tid;
        float a = 0.f, bsum = 0.f;
        #pragma unroll
        for (int j = 0; j < NQ; ++j) {
            a    += Lm[j][kcol] * qts[j];
            bsum += Lm[j][kcol] * qtts[j];
        }
        LTq[kcol] = a;
        t1s[kcol] = bsum;
    }
    __syncthreads();
    if (tid < NQ) {
        int kcol = tid;
        float a = 0.f;
        #pragma unroll
        for (int j = 0; j < NQ; ++j) a += Dq[j][kcol] * qts[j];
        u2[kcol] = a;
    }
    __syncthreads();
    if (tid < NQ) {
        int i = tid;
        float c1 = 0.f, c2 = 0.f, c3 = 0.f, c4 = 0.f;
        #pragma unroll
        for (int kk = 0; kk < NQ; ++kk) {
            c1 += Lm[i][kk] * t1s[kk];
            c2 += Lm[i][kk] * u2[kk];
            c3 += Dq[i][kk] * LTq[kk];
            c4 += Fj[i][kk] * LTq[kk];
        }
        out[i] = c1 + c2 + 0.5f * c3 - 0.5f * c4 + gvec[i];
    }
}

extern "C" void kernel_launch(void* const* d_in, const int* in_sizes, int n_in,
                              void* d_out, int out_size, void* d_ws, size_t ws_size,
                              hipStream_t stream) {
    const float* q    = (const float*)d_in[0];
    const float* q_t  = (const float*)d_in[1];
    const float* q_tt = (const float*)d_in[2];
    const float* W1   = (const float*)d_in[3];
    const float* b1   = (const float*)d_in[4];
    const float* W2   = (const float*)d_in[5];
    const float* b2   = (const float*)d_in[6];
    const float* W3   = (const float*)d_in[7];
    const float* b3   = (const float*)d_in[8];
    const float* Wd   = (const float*)d_in[9];
    const float* bd   = (const float*)d_in[10];
    const float* Wo   = (const float*)d_in[11];
    const float* bo   = (const float*)d_in[12];
    const float* Wg1  = (const float*)d_in[13];
    const float* bg1  = (const float*)d_in[14];
    const float* Wg2  = (const float*)d_in[15];
    const float* bg2  = (const float*)d_in[16];
    const float* Wg3  = (const float*)d_in[17];
    const float* bg3  = (const float*)d_in[18];

    float* ws = (float*)d_ws;
    float* Y       = ws;                   // 33*512 = 16896 (col 0 = h2)
    float* g2      = ws + 16896;           // 512
    float* Z       = ws + 17408;           // 33*512 = 16896 (col 0 = h3)
    float* gvec    = ws + 34304;           // 32
    float* U       = ws + 34336;           // 33*528 = 17424
    float* out     = (float*)d_out;

    hipLaunchKernelGGL(ka, dim3(272), dim3(256), 0, stream,
                       q, W1, b1, W2, b2, Wg1, bg1, Wg2, bg2, Y, g2);
    hipLaunchKernelGGL(kb, dim3(265), dim3(256), 0, stream,
                       W3, b3, Wg3, bg3, Y, g2, Z, gvec);
    hipLaunchKernelGGL(kc, dim3(264), dim3(256), 0, stream,
                       Wd, Wo, Z, U);
    hipLaunchKernelGGL(kd, dim3(1), dim3(256), 0, stream,
                       U, bd, bo, q_t, q_tt, gvec, out);
}